// Round 9
// baseline (224.146 us; speedup 1.0000x reference)
//
#include <hip/hip_runtime.h>

typedef unsigned short ushort_t;
typedef __bf16 bf16x8 __attribute__((ext_vector_type(8)));
typedef short short4v __attribute__((ext_vector_type(4)));
typedef float f32x4 __attribute__((ext_vector_type(4)));
typedef unsigned int uint4v __attribute__((ext_vector_type(4)));
typedef unsigned int uint2v __attribute__((ext_vector_type(2)));

#define NTOK 4096
#define DMODEL 256
#define DK 64
#define BS 8
#define LN2INV 1.44269504088896f

__device__ __forceinline__ ushort_t f2bf(float f) {
  unsigned u = __builtin_bit_cast(unsigned, f);
  u += 0x7fffu + ((u >> 16) & 1u);
  return (ushort_t)(u >> 16);
}
__device__ __forceinline__ float bf2f(ushort_t s) {
  return __builtin_bit_cast(float, ((unsigned)s) << 16);
}
__device__ __forceinline__ bf16x8 lds_frag(const ushort_t* p) {
  return __builtin_bit_cast(bf16x8, *(const uint4v*)p);
}
__device__ __forceinline__ bf16x8 ldg8(const ushort_t* p) {
  return __builtin_bit_cast(bf16x8, *(const uint4v*)p);
}
__device__ __forceinline__ short4v lo8(uint4v v) {
  uint2v t; t.x = v.x; t.y = v.y;
  return __builtin_bit_cast(short4v, t);
}
__device__ __forceinline__ short4v hi8(uint4v v) {
  uint2v t; t.x = v.z; t.y = v.w;
  return __builtin_bit_cast(short4v, t);
}
__device__ __forceinline__ float fexp2(float x) {
#if __has_builtin(__builtin_amdgcn_exp2f)
  return __builtin_amdgcn_exp2f(x);
#else
  return exp2f(x);
#endif
}
// pack hi16(x) | hi16(y)<<16 in one v_perm (bf16 truncation)
__device__ __forceinline__ unsigned bfpack(float x, float y) {
  return __builtin_amdgcn_perm(__builtin_bit_cast(unsigned, y),
                               __builtin_bit_cast(unsigned, x), 0x07060302u);
}
// K=16 bf16 MFMA: A[m=lane&15][k=quad*4+j], B[k=quad*4+j][n=lane&15], C: n=lane&15, m=quad*4+reg
__device__ __forceinline__ f32x4 mfma16(short4v a, short4v b, f32x4 c) {
#if defined(__HIP_DEVICE_COMPILE__)
#if __has_builtin(__builtin_amdgcn_mfma_f32_16x16x16bf16_1k)
  return __builtin_amdgcn_mfma_f32_16x16x16bf16_1k(a, b, c, 0, 0, 0);
#else
  typedef __bf16 bf16x4 __attribute__((ext_vector_type(4)));
  return __builtin_amdgcn_mfma_f32_16x16x16_bf16(__builtin_bit_cast(bf16x4, a),
                                                 __builtin_bit_cast(bf16x4, b), c, 0, 0, 0);
#endif
#else
  (void)a; (void)b;
  return c;  // host pass: never executed
#endif
}

// async global->LDS DMA, 16B per lane; dest = (uniform base) + lane*16
typedef __attribute__((address_space(3))) unsigned int lds_u32;
typedef const __attribute__((address_space(1))) unsigned int glob_u32;
__device__ __forceinline__ void gll16(const void* g, void* l) {
#if defined(__HIP_DEVICE_COMPILE__)
  __builtin_amdgcn_global_load_lds((glob_u32*)g, (lds_u32*)l, 16, 0, 0);
#else
  (void)g; (void)l;
#endif
}

// ----- k_convert: W fp32 -> bf16; Q rows pre-scaled by 1/ln2 (exp2 trick) --
__global__ __launch_bounds__(256) void k_convert(const float* __restrict__ Wqkv,
                                                 const float* __restrict__ Wout,
                                                 ushort_t* __restrict__ Wb,
                                                 ushort_t* __restrict__ Woutb) {
  int i = blockIdx.x * 256 + threadIdx.x;  // 256 blocks: 65536 total
  if (i < 3 * DK * DMODEL) {
    float w = Wqkv[i];
    if (i < DK * DMODEL) w *= LN2INV;  // Q rows
    Wb[i] = f2bf(w);
  } else {
    int j = i - 3 * DK * DMODEL;
    Woutb[j] = f2bf(Wout[j]);
  }
}

// ---------------- k1 v4: qkv = Wqkv @ x ; fused transpose + coalesced out --
__global__ __launch_bounds__(256) void k_qkv(const float* __restrict__ x,
                                             const ushort_t* __restrict__ W,
                                             ushort_t* __restrict__ QT,
                                             ushort_t* __restrict__ KT,
                                             ushort_t* __restrict__ Vf) {
  const int b = blockIdx.y;
  const int n0 = blockIdx.x * 64;
  const int tid = threadIdx.x;
  const int lane = tid & 63, wv = tid >> 6;
  const int quad = lane >> 4, l15 = lane & 15;
  __shared__ __align__(16) ushort_t lx[64 * 264];
  __shared__ __align__(16) ushort_t t[64 * 72];

  const float* xb = x + (size_t)b * DMODEL * NTOK;

  // ---- transpose prologue: 4 chunks of 64 c ----
#pragma unroll 1
  for (int cc = 0; cc < 4; cc++) {
    const int c0chunk = cc * 64;
#pragma unroll
    for (int kr = 0; kr < 2; kr++) {
      int s = tid + 256 * kr;
      int c = s >> 3, ns = (s & 7) * 8;
      const float* src = xb + (size_t)(c0chunk + c) * NTOK + n0 + ns;
      f32x4 a = *(const f32x4*)src;
      f32x4 bq = *(const f32x4*)(src + 4);
      uint4v o;
      o.x = (unsigned)f2bf(a[0]) | ((unsigned)f2bf(a[1]) << 16);
      o.y = (unsigned)f2bf(a[2]) | ((unsigned)f2bf(a[3]) << 16);
      o.z = (unsigned)f2bf(bq[0]) | ((unsigned)f2bf(bq[1]) << 16);
      o.w = (unsigned)f2bf(bq[2]) | ((unsigned)f2bf(bq[3]) << 16);
      *(uint4v*)(t + c * 72 + ns) = o;
    }
    __syncthreads();
#pragma unroll
    for (int kr = 0; kr < 2; kr++) {
      int s = tid + 256 * kr;
      int n = s >> 3, cs = (s & 7) * 8;
      unsigned e0 = t[(cs + 0) * 72 + n], e1 = t[(cs + 1) * 72 + n];
      unsigned e2 = t[(cs + 2) * 72 + n], e3 = t[(cs + 3) * 72 + n];
      unsigned e4 = t[(cs + 4) * 72 + n], e5 = t[(cs + 5) * 72 + n];
      unsigned e6 = t[(cs + 6) * 72 + n], e7 = t[(cs + 7) * 72 + n];
      uint4v o;
      o.x = e0 | (e1 << 16); o.y = e2 | (e3 << 16);
      o.z = e4 | (e5 << 16); o.w = e6 | (e7 << 16);
      *(uint4v*)(lx + n * 264 + c0chunk + cs) = o;
    }
    __syncthreads();
  }

  // ---- main loop: barrier-free ----
  f32x4 acc[3][4];
  const f32x4 zero4 = {0.f, 0.f, 0.f, 0.f};
#pragma unroll
  for (int i = 0; i < 3; i++)
#pragma unroll
    for (int j = 0; j < 4; j++) acc[i][j] = zero4;

#pragma unroll
  for (int c0 = 0; c0 < DMODEL; c0 += 32) {
    bf16x8 aw[3];
#pragma unroll
    for (int mt = 0; mt < 3; mt++)
      aw[mt] = ldg8(W + (wv * 48 + mt * 16 + l15) * DMODEL + c0 + quad * 8);
    bf16x8 bb[4];
#pragma unroll
    for (int nt = 0; nt < 4; nt++)
      bb[nt] = lds_frag(lx + (nt * 16 + l15) * 264 + c0 + quad * 8);
#pragma unroll
    for (int mt = 0; mt < 3; mt++)
#pragma unroll
      for (int nt = 0; nt < 4; nt++)
        acc[mt][nt] = __builtin_amdgcn_mfma_f32_16x16x32_bf16(aw[mt], bb[nt], acc[mt][nt], 0, 0, 0);
  }

  // ---- epilogue: stage in LDS (overlay lx), then coalesced stores ----
  __syncthreads();  // all waves done reading lx
  ushort_t* qk_t = lx;            // 128 rows x 68 shorts (Q rows 0-63, K rows 64-127)
  ushort_t* v_t = lx + 128 * 68;  // 4096 shorts: the block's contiguous Vf tile
#pragma unroll
  for (int mt = 0; mt < 3; mt++) {
    int o = wv * 48 + mt * 16 + quad * 4;
#pragma unroll
    for (int nt = 0; nt < 4; nt++) {
      int nl = nt * 16 + l15;
      f32x4 v4 = acc[mt][nt];
      if (o < 128) {
        uint2v ww;
        ww.x = (unsigned)f2bf(v4[0]) | ((unsigned)f2bf(v4[1]) << 16);
        ww.y = (unsigned)f2bf(v4[2]) | ((unsigned)f2bf(v4[3]) << 16);
        int row = (o < 64) ? nl : 64 + nl;
        *(uint2v*)(qk_t + row * 68 + (o & 63)) = ww;
      } else {
        int dbase = o - 128;
        int idx = (nt * 2 + (dbase >> 5)) * 512 + ((l15 >> 2) << 7) +
                  ((dbase & 15) << 3) + (((dbase >> 4) & 1) << 2) + (l15 & 3);
#pragma unroll
        for (int r = 0; r < 4; r++) v_t[idx + (r << 3)] = f2bf(v4[r]);
      }
    }
  }
  __syncthreads();
  {
    ushort_t* QTb = QT + ((size_t)b * NTOK + n0) * DK;
    ushort_t* KTb = KT + ((size_t)b * NTOK + n0) * DK;
#pragma unroll
    for (int k = 0; k < 4; k++) {
      int s = tid + 256 * k;
      int row = s >> 3, seg = (s & 7) * 8;
      uint4v val = *(const uint4v*)(qk_t + row * 68 + seg);
      ushort_t* dst = (row < 64) ? (QTb + (size_t)row * DK + seg)
                                 : (KTb + (size_t)(row - 64) * DK + seg);
      *(uint4v*)dst = val;
    }
    ushort_t* Vtile = Vf + ((size_t)b * 64 + (n0 >> 6)) * 4096;
    *(uint4v*)(Vtile + tid * 8) = *(const uint4v*)(v_t + tid * 8);
    *(uint4v*)(Vtile + 2048 + tid * 8) = *(const uint4v*)(v_t + 2048 + tid * 8);
  }
}

// ---- k_rsum v6: full-j blocks, merge + -log2 fused ------------------------
__global__ __launch_bounds__(512, 4) void k_rsum(const ushort_t* __restrict__ QT,
                                                 const ushort_t* __restrict__ KT,
                                                 float* __restrict__ Rr) {
  const int id = blockIdx.x;                 // 512 blocks
  const int b = id & 7;                      // XCD affinity
  const int i0 = (id >> 3) * 64;
  const int tid = threadIdx.x;
  const int lane = tid & 63, wv = tid >> 6;  // wv in [0,8)
  const int quad = lane >> 4, l15 = lane & 15;
  __shared__ __align__(16) float partial[8 * 64];
  const ushort_t* QTb = QT + ((size_t)b * NTOK + i0) * DK;
  const ushort_t* KTb = KT + ((size_t)b * NTOK + wv * 512) * DK;

  // Q fragments for all 64 i's (one-time, coalesced)
  bf16x8 aq0[4], aq1[4];
#pragma unroll
  for (int isub = 0; isub < 4; isub++) {
    const ushort_t* qp = QTb + (size_t)(isub * 16 + l15) * DK + quad * 8;
    aq0[isub] = ldg8(qp);
    aq1[isub] = ldg8(qp + 32);
  }

  f32x4 racc[4];
  const f32x4 zero4 = {0.f, 0.f, 0.f, 0.f};
#pragma unroll
  for (int isub = 0; isub < 4; isub++) racc[isub] = zero4;

#pragma unroll 1
  for (int ph = 0; ph < 8; ph++) {
    const ushort_t* kb_base = KTb + (size_t)ph * 64 * DK;
    bf16x8 kb0[4], kb1[4];
#pragma unroll
    for (int nt = 0; nt < 4; nt++) {
      const ushort_t* kp = kb_base + (size_t)(nt * 16 + l15) * DK + quad * 8;
      kb0[nt] = ldg8(kp);
      kb1[nt] = ldg8(kp + 32);
    }
#pragma unroll
    for (int isub = 0; isub < 4; isub++)
#pragma unroll
      for (int nt = 0; nt < 4; nt++) {
        f32x4 s4 = __builtin_amdgcn_mfma_f32_16x16x32_bf16(aq0[isub], kb0[nt], zero4, 0, 0, 0);
        s4 = __builtin_amdgcn_mfma_f32_16x16x32_bf16(aq1[isub], kb1[nt], s4, 0, 0, 0);
        racc[isub][0] += fexp2(s4[0]);
        racc[isub][1] += fexp2(s4[1]);
        racc[isub][2] += fexp2(s4[2]);
        racc[isub][3] += fexp2(s4[3]);
      }
  }

  // reduce over the 16 j-lanes (l15); quad bits untouched by masks 1,2,4,8
#pragma unroll
  for (int isub = 0; isub < 4; isub++)
#pragma unroll
    for (int r = 0; r < 4; r++) {
      float v = racc[isub][r];
      v += __shfl_xor(v, 1);
      v += __shfl_xor(v, 2);
      v += __shfl_xor(v, 4);
      v += __shfl_xor(v, 8);
      racc[isub][r] = v;
    }
  if (l15 == 0) {
#pragma unroll
    for (int isub = 0; isub < 4; isub++)
      *(f32x4*)(partial + wv * 64 + isub * 16 + quad * 4) = racc[isub];
  }
  __syncthreads();
  if (tid < 64) {
    float s = 0.f;
#pragma unroll
    for (int w = 0; w < 8; w++) s += partial[w * 64 + tid];
    Rr[(size_t)b * NTOK + i0 + tid] = -__log2f(s);
  }
}

// ---- k_pv v9: full async DMA dbuf (v7 pipeline) @ LDS 32768 = 4 blocks/CU.
// lr via one-ahead register pinned by the asm memory clobbers (loads can't
// cross the vmcnt asm). vmcnt(5) per iter drains only the PREVIOUS group
// {4 gll16 + lr}, issued ~1 iter (~800cy) earlier -> zero exposed latency.
// ZERO barriers until epilogue; wave-private LDS slots.
__global__ __launch_bounds__(256, 4) void k_pv(const ushort_t* __restrict__ QT,
                                               const ushort_t* __restrict__ KT,
                                               const ushort_t* __restrict__ Vf,
                                               const float* __restrict__ Rr,
                                               ushort_t* __restrict__ Yp) {
  const int id = blockIdx.x;                 // 1024 blocks
  const int b = id & 7;                      // XCD affinity
  const int rest = id >> 3;
  const int j0 = (rest & 63) * 64;
  const int ih = rest >> 6;                  // i half
  const int tid = threadIdx.x;
  const int lane = tid & 63, wv = tid >> 6;
  const int quad = lane >> 4, l15 = lane & 15;

  __shared__ __align__(16) ushort_t pool[16384];   // 32768 B
  ushort_t* wbuf = pool + wv * 4096;               // wave dbuf: 2 x 2048 shorts
  float* rbuf = (float*)pool;                      // epilogue overlay: 64x68 f32
  ushort_t* pbuf = pool + 8704;                    // epilogue: byte 17408

  const ushort_t* KTb = KT + ((size_t)b * NTOK + j0) * DK;
  const ushort_t* QTb = QT + ((size_t)b * NTOK + ih * 2048) * DK;
  const ushort_t* Vfb = Vf + ((size_t)b * 64 + ih * 32) * 4096;  // 8KB tiles
  const float* Rrb = Rr + (size_t)b * NTOK + ih * 2048;

  const int qrow = (wv * 16 + l15) * DK + quad * 8;
  const int vfo = wv * 1024 + lane * 8;
  const int lro = wv * 16 + quad * 4;

  // prologue: issue it0 DMA group + lr0; then K tile loads
  gll16(QTb + qrow,       wbuf);
  gll16(QTb + qrow + 32,  wbuf + 512);
  gll16(Vfb + vfo,        wbuf + 1024);
  gll16(Vfb + vfo + 512,  wbuf + 1536);
  f32x4 lrcur = *(const f32x4*)(Rrb + lro);

  bf16x8 kb0[4], kb1[4];
#pragma unroll
  for (int nt = 0; nt < 4; nt++) {
    const ushort_t* kp = KTb + (size_t)(nt * 16 + l15) * DK + quad * 8;
    kb0[nt] = ldg8(kp);
    kb1[nt] = ldg8(kp + 32);
  }

  f32x4 yt[4][4];
  const f32x4 zero4 = {0.f, 0.f, 0.f, 0.f};
#pragma unroll
  for (int i = 0; i < 4; i++)
#pragma unroll
    for (int j = 0; j < 4; j++) yt[i][j] = zero4;

#pragma unroll 1
  for (int it = 0; it < 32; it++) {
    const int cb = it & 1, nb = cb ^ 1;
    const int tpre = (it + 1 < 32) ? it + 1 : 31;  // dummy at tail keeps vmcnt math
    {
      const ushort_t* qp = QTb + (size_t)tpre * 64 * DK + qrow;
      const ushort_t* vp = Vfb + (size_t)tpre * 4096 + vfo;
      ushort_t* nbuf = wbuf + nb * 2048;
      gll16(qp,       nbuf);
      gll16(qp + 32,  nbuf + 512);
      gll16(vp,       nbuf + 1024);
      gll16(vp + 512, nbuf + 1536);
    }
    f32x4 lrnext = *(const f32x4*)(Rrb + tpre * 64 + lro);
    asm volatile("s_waitcnt vmcnt(5)" ::: "memory");  // drains prev {4 gll + lr}
    __builtin_amdgcn_sched_barrier(0);
    const ushort_t* cbuf = wbuf + cb * 2048;
    bf16x8 a0 = lds_frag(cbuf + lane * 8);
    bf16x8 a1 = lds_frag(cbuf + 512 + lane * 8);
    uint4v vv0 = *(const uint4v*)(cbuf + 1024 + lane * 8);
    uint4v vv1 = *(const uint4v*)(cbuf + 1536 + lane * 8);
    short4v vf0 = lo8(vv0), vf1 = hi8(vv0), vf2 = lo8(vv1), vf3 = hi8(vv1);
#pragma unroll
    for (int nt = 0; nt < 4; nt++) {
      f32x4 s4 = __builtin_amdgcn_mfma_f32_16x16x32_bf16(a0, kb0[nt], lrcur, 0, 0, 0);
      s4 = __builtin_amdgcn_mfma_f32_16x16x32_bf16(a1, kb1[nt], s4, 0, 0, 0);
      uint2v wp;
      wp.x = bfpack(fexp2(s4[0]), fexp2(s4[1]));
      wp.y = bfpack(fexp2(s4[2]), fexp2(s4[3]));
      short4v wf = __builtin_bit_cast(short4v, wp);
      yt[nt][0] = mfma16(wf, vf0, yt[nt][0]);
      yt[nt][1] = mfma16(wf, vf1, yt[nt][1]);
      yt[nt][2] = mfma16(wf, vf2, yt[nt][2]);
      yt[nt][3] = mfma16(wf, vf3, yt[nt][3]);
    }
    lrcur = lrnext;
  }

  asm volatile("s_waitcnt vmcnt(0)" ::: "memory");  // drain tail prefetch
  __syncthreads();  // all waves out of dbuf region before overlay

  // cross-wave reduction into rbuf[d][j], then bf16 pbuf[j][d]
  if (wv == 0) {
#pragma unroll
    for (int nt = 0; nt < 4; nt++)
#pragma unroll
      for (int dsub = 0; dsub < 4; dsub++)
        *(f32x4*)(rbuf + (dsub * 16 + l15) * 68 + nt * 16 + quad * 4) = yt[nt][dsub];
  }
  __syncthreads();
  if (wv == 1) {
#pragma unroll
    for (int nt = 0; nt < 4; nt++)
#pragma unroll
      for (int dsub = 0; dsub < 4; dsub++) {
        float* p = rbuf + (dsub * 16 + l15) * 68 + nt * 16 + quad * 4;
        *(f32x4*)p = *(const f32x4*)p + yt[nt][dsub];
      }
  }
  __syncthreads();
  if (wv == 2) {
#pragma unroll
    for (int nt = 0; nt < 4; nt++)
#pragma unroll
      for (int dsub = 0; dsub < 4; dsub++) {
        float* p = rbuf + (dsub * 16 + l15) * 68 + nt * 16 + quad * 4;
        *(f32x4*)p = *(const f32x4*)p + yt[nt][dsub];
      }
  }
  __syncthreads();
  if (wv == 3) {
#pragma unroll
    for (int nt = 0; nt < 4; nt++)
#pragma unroll
      for (int dsub = 0; dsub < 4; dsub++) {
        const float* p = rbuf + (dsub * 16 + l15) * 68 + nt * 16 + quad * 4;
        f32x4 v4 = *(const f32x4*)p + yt[nt][dsub];
#pragma unroll
        for (int r = 0; r < 4; r++)
          pbuf[(nt * 16 + quad * 4 + r) * 72 + dsub * 16 + l15] = f2bf(v4[r]);
      }
  }
  __syncthreads();

  // coalesced copy pbuf -> Yp[ih][b][j0+row][d]
  ushort_t* Ypb = Yp + ((size_t)(ih * 8 + b) * NTOK + j0) * DK;
#pragma unroll
  for (int kr = 0; kr < 2; kr++) {
    int s = tid + 256 * kr;
    int row = s >> 3, cc = (s & 7) * 8;
    *(uint4v*)(Ypb + (size_t)row * DK + cc) = *(const uint4v*)(pbuf + row * 72 + cc);
  }
}

// ---- k_out: y = Yp0 + Yp1 ; o = Wout @ y * gamma + x --------------------
__global__ __launch_bounds__(256) void k_out(const ushort_t* __restrict__ Yp,
                                             const ushort_t* __restrict__ Wout,
                                             const float* __restrict__ gammap,
                                             const float* __restrict__ x,
                                             float* __restrict__ outp) {
  const int id = blockIdx.x;                 // 512 blocks
  const int b = id & 7;
  const int n0 = (id >> 3) * 64;
  const int tid = threadIdx.x;
  const int lane = tid & 63, wv = tid >> 6;
  const int quad = lane >> 4, l15 = lane & 15;
  __shared__ __align__(16) ushort_t pbuf[64 * 72];

  const ushort_t* Y0 = Yp + ((size_t)b * NTOK + n0) * DK;
  const ushort_t* Y1 = Yp + ((size_t)(8 + b) * NTOK + n0) * DK;
#pragma unroll
  for (int kr = 0; kr < 2; kr++) {
    int s = tid + 256 * kr;
    int row = s >> 3, c8 = (s & 7) * 8;
    uint4v ua = *(const uint4v*)(Y0 + (size_t)row * DK + c8);
    uint4v ub = *(const uint4v*)(Y1 + (size_t)row * DK + c8);
    uint4v oc;
    unsigned* pa = (unsigned*)&ua;
    unsigned* pb = (unsigned*)&ub;
    unsigned* po = (unsigned*)&oc;
#pragma unroll
    for (int w = 0; w < 4; w++) {
      float lo = bf2f((ushort_t)(pa[w] & 0xffff)) + bf2f((ushort_t)(pb[w] & 0xffff));
      float hi = bf2f((ushort_t)(pa[w] >> 16)) + bf2f((ushort_t)(pb[w] >> 16));
      po[w] = bfpack(lo, hi);
    }
    *(uint4v*)(pbuf + row * 72 + c8) = oc;
  }
  __syncthreads();

  const f32x4 zero4 = {0.f, 0.f, 0.f, 0.f};
  bf16x8 yb0[4], yb1[4];
#pragma unroll
  for (int nt = 0; nt < 4; nt++) {
    yb0[nt] = lds_frag(pbuf + (nt * 16 + l15) * 72 + quad * 8);
    yb1[nt] = lds_frag(pbuf + (nt * 16 + l15) * 72 + 32 + quad * 8);
  }
  f32x4 oacc[4][4];
#pragma unroll
  for (int m = 0; m < 4; m++)
#pragma unroll
    for (int nt = 0; nt < 4; nt++) oacc[m][nt] = zero4;
#pragma unroll
  for (int m = 0; m < 4; m++) {
    int c = (wv * 4 + m) * 16 + l15;
    bf16x8 aw0 = __builtin_bit_cast(bf16x8, *(const uint4v*)(Wout + c * DK + quad * 8));
    bf16x8 aw1 = __builtin_bit_cast(bf16x8, *(const uint4v*)(Wout + c * DK + 32 + quad * 8));
#pragma unroll
    for (int nt = 0; nt < 4; nt++) {
      oacc[m][nt] = __builtin_amdgcn_mfma_f32_16x16x32_bf16(aw0, yb0[nt], oacc[m][nt], 0, 0, 0);
      oacc[m][nt] = __builtin_amdgcn_mfma_f32_16x16x32_bf16(aw1, yb1[nt], oacc[m][nt], 0, 0, 0);
    }
  }
  float g = gammap[0];
  const float* xb = x + (size_t)b * DMODEL * NTOK;
  float* ob = outp + (size_t)b * DMODEL * NTOK;
#pragma unroll
  for (int m = 0; m < 4; m++) {
    int cbase = (wv * 4 + m) * 16 + quad * 4;
#pragma unroll
    for (int nt = 0; nt < 4; nt++) {
      int n = n0 + nt * 16 + l15;
#pragma unroll
      for (int r = 0; r < 4; r++) {
        size_t idx = (size_t)(cbase + r) * NTOK + n;
        ob[idx] = oacc[m][nt][r] * g + xb[idx];
      }
    }
  }
}

extern "C" void kernel_launch(void* const* d_in, const int* in_sizes, int n_in,
                              void* d_out, int out_size, void* d_ws, size_t ws_size,
                              hipStream_t stream) {
  const float* v = (const float*)d_in[0];
  const float* Wqkv = (const float*)d_in[1];
  const float* Wout = (const float*)d_in[2];
  const float* gamma = (const float*)d_in[3];
  float* outp = (float*)d_out;

  ushort_t* QT = (ushort_t*)d_ws;                      // 8*4096*64 bf16
  ushort_t* KT = QT + (size_t)BS * NTOK * DK;
  ushort_t* Vf = KT + (size_t)BS * NTOK * DK;          // fragment-order V
  ushort_t* Wb = Vf + (size_t)BS * DK * NTOK;          // 192*256
  ushort_t* Woutb = Wb + 3 * DK * DMODEL;              // 256*64
  float* Rr = (float*)(Woutb + DMODEL * DK);           // 8*4096 f32
  ushort_t* Yp = (ushort_t*)(Rr + (size_t)BS * NTOK);  // 2*8*4096*64 bf16

  k_convert<<<dim3(256), 256, 0, stream>>>(Wqkv, Wout, Wb, Woutb);
  k_qkv<<<dim3(64, BS), 256, 0, stream>>>(v, Wb, QT, KT, Vf);
  k_rsum<<<dim3(512), 512, 0, stream>>>(QT, KT, Rr);
  k_pv<<<dim3(1024), 256, 0, stream>>>(QT, KT, Vf, Rr, Yp);
  k_out<<<dim3(512), 256, 0, stream>>>(Yp, Woutb, gamma, v, outp);
}

// Round 10
// 201.022 us; speedup vs baseline: 1.1150x; 1.1150x over previous
//
#include <hip/hip_runtime.h>

typedef unsigned short ushort_t;
typedef __bf16 bf16x8 __attribute__((ext_vector_type(8)));
typedef short short4v __attribute__((ext_vector_type(4)));
typedef float f32x4 __attribute__((ext_vector_type(4)));
typedef unsigned int uint4v __attribute__((ext_vector_type(4)));
typedef unsigned int uint2v __attribute__((ext_vector_type(2)));

#define NTOK 4096
#define DMODEL 256
#define DK 64
#define BS 8
#define LN2INV 1.44269504088896f

__device__ __forceinline__ ushort_t f2bf(float f) {
  unsigned u = __builtin_bit_cast(unsigned, f);
  u += 0x7fffu + ((u >> 16) & 1u);
  return (ushort_t)(u >> 16);
}
__device__ __forceinline__ float bf2f(ushort_t s) {
  return __builtin_bit_cast(float, ((unsigned)s) << 16);
}
__device__ __forceinline__ bf16x8 lds_frag(const ushort_t* p) {
  return __builtin_bit_cast(bf16x8, *(const uint4v*)p);
}
__device__ __forceinline__ bf16x8 ldg8(const ushort_t* p) {
  return __builtin_bit_cast(bf16x8, *(const uint4v*)p);
}
__device__ __forceinline__ short4v lo8(uint4v v) {
  uint2v t; t.x = v.x; t.y = v.y;
  return __builtin_bit_cast(short4v, t);
}
__device__ __forceinline__ short4v hi8(uint4v v) {
  uint2v t; t.x = v.z; t.y = v.w;
  return __builtin_bit_cast(short4v, t);
}
__device__ __forceinline__ float fexp2(float x) {
#if __has_builtin(__builtin_amdgcn_exp2f)
  return __builtin_amdgcn_exp2f(x);
#else
  return exp2f(x);
#endif
}
// pack hi16(x) | hi16(y)<<16 in one v_perm (bf16 truncation)
__device__ __forceinline__ unsigned bfpack(float x, float y) {
  return __builtin_amdgcn_perm(__builtin_bit_cast(unsigned, y),
                               __builtin_bit_cast(unsigned, x), 0x07060302u);
}
// K=16 bf16 MFMA: A[m=lane&15][k=quad*4+j], B[k=quad*4+j][n=lane&15], C: n=lane&15, m=quad*4+reg
__device__ __forceinline__ f32x4 mfma16(short4v a, short4v b, f32x4 c) {
#if defined(__HIP_DEVICE_COMPILE__)
#if __has_builtin(__builtin_amdgcn_mfma_f32_16x16x16bf16_1k)
  return __builtin_amdgcn_mfma_f32_16x16x16bf16_1k(a, b, c, 0, 0, 0);
#else
  typedef __bf16 bf16x4 __attribute__((ext_vector_type(4)));
  return __builtin_amdgcn_mfma_f32_16x16x16_bf16(__builtin_bit_cast(bf16x4, a),
                                                 __builtin_bit_cast(bf16x4, b), c, 0, 0, 0);
#endif
#else
  (void)a; (void)b;
  return c;  // host pass: never executed
#endif
}

// async global->LDS DMA, 16B per lane; dest = (uniform base) + lane*16
typedef __attribute__((address_space(3))) unsigned int lds_u32;
typedef const __attribute__((address_space(1))) unsigned int glob_u32;
__device__ __forceinline__ void gll16(const void* g, void* l) {
#if defined(__HIP_DEVICE_COMPILE__)
  __builtin_amdgcn_global_load_lds((glob_u32*)g, (lds_u32*)l, 16, 0, 0);
#else
  (void)g; (void)l;
#endif
}

// ----- k_convert: W fp32 -> bf16; Q rows pre-scaled by 1/ln2 (exp2 trick) --
__global__ __launch_bounds__(256) void k_convert(const float* __restrict__ Wqkv,
                                                 const float* __restrict__ Wout,
                                                 ushort_t* __restrict__ Wb,
                                                 ushort_t* __restrict__ Woutb) {
  int i = blockIdx.x * 256 + threadIdx.x;  // 256 blocks: 65536 total
  if (i < 3 * DK * DMODEL) {
    float w = Wqkv[i];
    if (i < DK * DMODEL) w *= LN2INV;  // Q rows
    Wb[i] = f2bf(w);
  } else {
    int j = i - 3 * DK * DMODEL;
    Woutb[j] = f2bf(Wout[j]);
  }
}

// ---------------- k1 v4: qkv = Wqkv @ x ; fused transpose + coalesced out --
__global__ __launch_bounds__(256) void k_qkv(const float* __restrict__ x,
                                             const ushort_t* __restrict__ W,
                                             ushort_t* __restrict__ QT,
                                             ushort_t* __restrict__ KT,
                                             ushort_t* __restrict__ Vf) {
  const int b = blockIdx.y;
  const int n0 = blockIdx.x * 64;
  const int tid = threadIdx.x;
  const int lane = tid & 63, wv = tid >> 6;
  const int quad = lane >> 4, l15 = lane & 15;
  __shared__ __align__(16) ushort_t lx[64 * 264];
  __shared__ __align__(16) ushort_t t[64 * 72];

  const float* xb = x + (size_t)b * DMODEL * NTOK;

  // ---- transpose prologue: 4 chunks of 64 c ----
#pragma unroll 1
  for (int cc = 0; cc < 4; cc++) {
    const int c0chunk = cc * 64;
#pragma unroll
    for (int kr = 0; kr < 2; kr++) {
      int s = tid + 256 * kr;
      int c = s >> 3, ns = (s & 7) * 8;
      const float* src = xb + (size_t)(c0chunk + c) * NTOK + n0 + ns;
      f32x4 a = *(const f32x4*)src;
      f32x4 bq = *(const f32x4*)(src + 4);
      uint4v o;
      o.x = (unsigned)f2bf(a[0]) | ((unsigned)f2bf(a[1]) << 16);
      o.y = (unsigned)f2bf(a[2]) | ((unsigned)f2bf(a[3]) << 16);
      o.z = (unsigned)f2bf(bq[0]) | ((unsigned)f2bf(bq[1]) << 16);
      o.w = (unsigned)f2bf(bq[2]) | ((unsigned)f2bf(bq[3]) << 16);
      *(uint4v*)(t + c * 72 + ns) = o;
    }
    __syncthreads();
#pragma unroll
    for (int kr = 0; kr < 2; kr++) {
      int s = tid + 256 * kr;
      int n = s >> 3, cs = (s & 7) * 8;
      unsigned e0 = t[(cs + 0) * 72 + n], e1 = t[(cs + 1) * 72 + n];
      unsigned e2 = t[(cs + 2) * 72 + n], e3 = t[(cs + 3) * 72 + n];
      unsigned e4 = t[(cs + 4) * 72 + n], e5 = t[(cs + 5) * 72 + n];
      unsigned e6 = t[(cs + 6) * 72 + n], e7 = t[(cs + 7) * 72 + n];
      uint4v o;
      o.x = e0 | (e1 << 16); o.y = e2 | (e3 << 16);
      o.z = e4 | (e5 << 16); o.w = e6 | (e7 << 16);
      *(uint4v*)(lx + n * 264 + c0chunk + cs) = o;
    }
    __syncthreads();
  }

  // ---- main loop: barrier-free ----
  f32x4 acc[3][4];
  const f32x4 zero4 = {0.f, 0.f, 0.f, 0.f};
#pragma unroll
  for (int i = 0; i < 3; i++)
#pragma unroll
    for (int j = 0; j < 4; j++) acc[i][j] = zero4;

#pragma unroll
  for (int c0 = 0; c0 < DMODEL; c0 += 32) {
    bf16x8 aw[3];
#pragma unroll
    for (int mt = 0; mt < 3; mt++)
      aw[mt] = ldg8(W + (wv * 48 + mt * 16 + l15) * DMODEL + c0 + quad * 8);
    bf16x8 bb[4];
#pragma unroll
    for (int nt = 0; nt < 4; nt++)
      bb[nt] = lds_frag(lx + (nt * 16 + l15) * 264 + c0 + quad * 8);
#pragma unroll
    for (int mt = 0; mt < 3; mt++)
#pragma unroll
      for (int nt = 0; nt < 4; nt++)
        acc[mt][nt] = __builtin_amdgcn_mfma_f32_16x16x32_bf16(aw[mt], bb[nt], acc[mt][nt], 0, 0, 0);
  }

  // ---- epilogue: stage in LDS (overlay lx), then coalesced stores ----
  __syncthreads();  // all waves done reading lx
  ushort_t* qk_t = lx;            // 128 rows x 68 shorts (Q rows 0-63, K rows 64-127)
  ushort_t* v_t = lx + 128 * 68;  // 4096 shorts: the block's contiguous Vf tile
#pragma unroll
  for (int mt = 0; mt < 3; mt++) {
    int o = wv * 48 + mt * 16 + quad * 4;
#pragma unroll
    for (int nt = 0; nt < 4; nt++) {
      int nl = nt * 16 + l15;
      f32x4 v4 = acc[mt][nt];
      if (o < 128) {
        uint2v ww;
        ww.x = (unsigned)f2bf(v4[0]) | ((unsigned)f2bf(v4[1]) << 16);
        ww.y = (unsigned)f2bf(v4[2]) | ((unsigned)f2bf(v4[3]) << 16);
        int row = (o < 64) ? nl : 64 + nl;
        *(uint2v*)(qk_t + row * 68 + (o & 63)) = ww;
      } else {
        int dbase = o - 128;
        int idx = (nt * 2 + (dbase >> 5)) * 512 + ((l15 >> 2) << 7) +
                  ((dbase & 15) << 3) + (((dbase >> 4) & 1) << 2) + (l15 & 3);
#pragma unroll
        for (int r = 0; r < 4; r++) v_t[idx + (r << 3)] = f2bf(v4[r]);
      }
    }
  }
  __syncthreads();
  {
    ushort_t* QTb = QT + ((size_t)b * NTOK + n0) * DK;
    ushort_t* KTb = KT + ((size_t)b * NTOK + n0) * DK;
#pragma unroll
    for (int k = 0; k < 4; k++) {
      int s = tid + 256 * k;
      int row = s >> 3, seg = (s & 7) * 8;
      uint4v val = *(const uint4v*)(qk_t + row * 68 + seg);
      ushort_t* dst = (row < 64) ? (QTb + (size_t)row * DK + seg)
                                 : (KTb + (size_t)(row - 64) * DK + seg);
      *(uint4v*)dst = val;
    }
    ushort_t* Vtile = Vf + ((size_t)b * 64 + (n0 >> 6)) * 4096;
    *(uint4v*)(Vtile + tid * 8) = *(const uint4v*)(v_t + tid * 8);
    *(uint4v*)(Vtile + 2048 + tid * 8) = *(const uint4v*)(v_t + 2048 + tid * 8);
  }
}

// ---- k_rsum v6: full-j blocks, merge + -log2 fused ------------------------
__global__ __launch_bounds__(512, 4) void k_rsum(const ushort_t* __restrict__ QT,
                                                 const ushort_t* __restrict__ KT,
                                                 float* __restrict__ Rr) {
  const int id = blockIdx.x;                 // 512 blocks
  const int b = id & 7;                      // XCD affinity
  const int i0 = (id >> 3) * 64;
  const int tid = threadIdx.x;
  const int lane = tid & 63, wv = tid >> 6;  // wv in [0,8)
  const int quad = lane >> 4, l15 = lane & 15;
  __shared__ __align__(16) float partial[8 * 64];
  const ushort_t* QTb = QT + ((size_t)b * NTOK + i0) * DK;
  const ushort_t* KTb = KT + ((size_t)b * NTOK + wv * 512) * DK;

  // Q fragments for all 64 i's (one-time, coalesced)
  bf16x8 aq0[4], aq1[4];
#pragma unroll
  for (int isub = 0; isub < 4; isub++) {
    const ushort_t* qp = QTb + (size_t)(isub * 16 + l15) * DK + quad * 8;
    aq0[isub] = ldg8(qp);
    aq1[isub] = ldg8(qp + 32);
  }

  f32x4 racc[4];
  const f32x4 zero4 = {0.f, 0.f, 0.f, 0.f};
#pragma unroll
  for (int isub = 0; isub < 4; isub++) racc[isub] = zero4;

#pragma unroll 1
  for (int ph = 0; ph < 8; ph++) {
    const ushort_t* kb_base = KTb + (size_t)ph * 64 * DK;
    bf16x8 kb0[4], kb1[4];
#pragma unroll
    for (int nt = 0; nt < 4; nt++) {
      const ushort_t* kp = kb_base + (size_t)(nt * 16 + l15) * DK + quad * 8;
      kb0[nt] = ldg8(kp);
      kb1[nt] = ldg8(kp + 32);
    }
#pragma unroll
    for (int isub = 0; isub < 4; isub++)
#pragma unroll
      for (int nt = 0; nt < 4; nt++) {
        f32x4 s4 = __builtin_amdgcn_mfma_f32_16x16x32_bf16(aq0[isub], kb0[nt], zero4, 0, 0, 0);
        s4 = __builtin_amdgcn_mfma_f32_16x16x32_bf16(aq1[isub], kb1[nt], s4, 0, 0, 0);
        racc[isub][0] += fexp2(s4[0]);
        racc[isub][1] += fexp2(s4[1]);
        racc[isub][2] += fexp2(s4[2]);
        racc[isub][3] += fexp2(s4[3]);
      }
  }

  // reduce over the 16 j-lanes (l15); quad bits untouched by masks 1,2,4,8
#pragma unroll
  for (int isub = 0; isub < 4; isub++)
#pragma unroll
    for (int r = 0; r < 4; r++) {
      float v = racc[isub][r];
      v += __shfl_xor(v, 1);
      v += __shfl_xor(v, 2);
      v += __shfl_xor(v, 4);
      v += __shfl_xor(v, 8);
      racc[isub][r] = v;
    }
  if (l15 == 0) {
#pragma unroll
    for (int isub = 0; isub < 4; isub++)
      *(f32x4*)(partial + wv * 64 + isub * 16 + quad * 4) = racc[isub];
  }
  __syncthreads();
  if (tid < 64) {
    float s = 0.f;
#pragma unroll
    for (int w = 0; w < 8; w++) s += partial[w * 64 + tid];
    Rr[(size_t)b * NTOK + i0 + tid] = -__log2f(s);
  }
}

// ---- k_pv v7 (verbatim restore; best measured: 55.1 us) ------------------
// Full wave-private async DMA double-buffer (global_load_lds): prefetch lives
// in LDS (zero VGPR live ranges -> compiler can't dismantle, nothing spills);
// waits are explicit counted vmcnt(4); ZERO in-loop barriers (wave-private
// slots, lane reads back exactly the 16B it DMA'd). lr staged once as an
// 8KB LDS table (keeps the loop body free of plain global loads -> no
// spill, v8/v9 lesson). LDS total = 8K + 4 waves x 2 x 4KB = 40960 B.
__global__ __launch_bounds__(256, 4) void k_pv(const ushort_t* __restrict__ QT,
                                               const ushort_t* __restrict__ KT,
                                               const ushort_t* __restrict__ Vf,
                                               const float* __restrict__ Rr,
                                               ushort_t* __restrict__ Yp) {
  const int id = blockIdx.x;                 // 1024 blocks
  const int b = id & 7;                      // XCD affinity
  const int rest = id >> 3;
  const int j0 = (rest & 63) * 64;
  const int ih = rest >> 6;                  // i half
  const int tid = threadIdx.x;
  const int lane = tid & 63, wv = tid >> 6;
  const int quad = lane >> 4, l15 = lane & 15;

  __shared__ __align__(16) ushort_t pool[20480];   // 40960 B
  float* lrtab = (float*)pool;                     // bytes [0,8192): 2048 f32
  ushort_t* wbuf = pool + 4096 + wv * 4096;        // wave dbuf: 2 x 2048 shorts
  float* rbuf = (float*)pool;                      // epilogue overlay: 64x68 f32
  ushort_t* pbuf = pool + 8704;                    // epilogue: byte 17408

  const ushort_t* KTb = KT + ((size_t)b * NTOK + j0) * DK;
  const ushort_t* QTb = QT + ((size_t)b * NTOK + ih * 2048) * DK;
  const ushort_t* Vfb = Vf + ((size_t)b * 64 + ih * 32) * 4096;  // 8KB tiles
  const float* Rrb = Rr + (size_t)b * NTOK + ih * 2048;

  const int qrow = (wv * 16 + l15) * DK + quad * 8;
  const int vfo = wv * 1024 + lane * 8;

  // issue it0 DMA first (overlaps lr-table staging + K loads)
  gll16(QTb + qrow,       wbuf);
  gll16(QTb + qrow + 32,  wbuf + 512);
  gll16(Vfb + vfo,        wbuf + 1024);
  gll16(Vfb + vfo + 512,  wbuf + 1536);

  // lr table: 2048 f32, cooperative coalesced
  {
    f32x4 r0 = *(const f32x4*)(Rrb + tid * 8);
    f32x4 r1 = *(const f32x4*)(Rrb + tid * 8 + 4);
    *(f32x4*)(lrtab + tid * 8) = r0;
    *(f32x4*)(lrtab + tid * 8 + 4) = r1;
  }

  // resident K tile, one-time direct-global per wave
  bf16x8 kb0[4], kb1[4];
#pragma unroll
  for (int nt = 0; nt < 4; nt++) {
    const ushort_t* kp = KTb + (size_t)(nt * 16 + l15) * DK + quad * 8;
    kb0[nt] = ldg8(kp);
    kb1[nt] = ldg8(kp + 32);
  }

  __syncthreads();  // lrtab visible; drains vmcnt -> buf0 complete

  f32x4 yt[4][4];
  const f32x4 zero4 = {0.f, 0.f, 0.f, 0.f};
#pragma unroll
  for (int i = 0; i < 4; i++)
#pragma unroll
    for (int j = 0; j < 4; j++) yt[i][j] = zero4;

#pragma unroll 1
  for (int it = 0; it < 32; it++) {
    const int cb = it & 1, nb = cb ^ 1;
    const int tpre = (it + 1 < 32) ? it + 1 : 31;  // always issue (keeps vmcnt math)
    {
      const ushort_t* qp = QTb + (size_t)tpre * 64 * DK + qrow;
      const ushort_t* vp = Vfb + (size_t)tpre * 4096 + vfo;
      ushort_t* nbuf = wbuf + nb * 2048;
      gll16(qp,       nbuf);
      gll16(qp + 32,  nbuf + 512);
      gll16(vp,       nbuf + 1024);
      gll16(vp + 512, nbuf + 1536);
    }
    asm volatile("s_waitcnt vmcnt(4)" ::: "memory");  // prev it's DMA done
    __builtin_amdgcn_sched_barrier(0);
    const ushort_t* cbuf = wbuf + cb * 2048;
    bf16x8 a0 = lds_frag(cbuf + lane * 8);
    bf16x8 a1 = lds_frag(cbuf + 512 + lane * 8);
    uint4v vv0 = *(const uint4v*)(cbuf + 1024 + lane * 8);
    uint4v vv1 = *(const uint4v*)(cbuf + 1536 + lane * 8);
    f32x4 lrv = *(const f32x4*)(lrtab + it * 64 + wv * 16 + quad * 4);
    short4v vf0 = lo8(vv0), vf1 = hi8(vv0), vf2 = lo8(vv1), vf3 = hi8(vv1);
#pragma unroll
    for (int nt = 0; nt < 4; nt++) {
      f32x4 s4 = __builtin_amdgcn_mfma_f32_16x16x32_bf16(a0, kb0[nt], lrv, 0, 0, 0);
      s4 = __builtin_amdgcn_mfma_f32_16x16x32_bf16(a1, kb1[nt], s4, 0, 0, 0);
      uint2v wp;
      wp.x = bfpack(fexp2(s4[0]), fexp2(s4[1]));
      wp.y = bfpack(fexp2(s4[2]), fexp2(s4[3]));
      short4v wf = __builtin_bit_cast(short4v, wp);
      yt[nt][0] = mfma16(wf, vf0, yt[nt][0]);
      yt[nt][1] = mfma16(wf, vf1, yt[nt][1]);
      yt[nt][2] = mfma16(wf, vf2, yt[nt][2]);
      yt[nt][3] = mfma16(wf, vf3, yt[nt][3]);
    }
  }

  asm volatile("s_waitcnt vmcnt(0)" ::: "memory");  // drain dummy prefetch
  __syncthreads();  // all waves out of dbuf region before overlay

  // cross-wave reduction into rbuf[d][j], then bf16 pbuf[j][d]
  if (wv == 0) {
#pragma unroll
    for (int nt = 0; nt < 4; nt++)
#pragma unroll
      for (int dsub = 0; dsub < 4; dsub++)
        *(f32x4*)(rbuf + (dsub * 16 + l15) * 68 + nt * 16 + quad * 4) = yt[nt][dsub];
  }
  __syncthreads();
  if (wv == 1) {
#pragma unroll
    for (int nt = 0; nt < 4; nt++)
#pragma unroll
      for (int dsub = 0; dsub < 4; dsub++) {
        float* p = rbuf + (dsub * 16 + l15) * 68 + nt * 16 + quad * 4;
        *(f32x4*)p = *(const f32x4*)p + yt[nt][dsub];
      }
  }
  __syncthreads();
  if (wv == 2) {
#pragma unroll
    for (int nt = 0; nt < 4; nt++)
#pragma unroll
      for (int dsub = 0; dsub < 4; dsub++) {
        float* p = rbuf + (dsub * 16 + l15) * 68 + nt * 16 + quad * 4;
        *(f32x4*)p = *(const f32x4*)p + yt[nt][dsub];
      }
  }
  __syncthreads();
  if (wv == 3) {
#pragma unroll
    for (int nt = 0; nt < 4; nt++)
#pragma unroll
      for (int dsub = 0; dsub < 4; dsub++) {
        const float* p = rbuf + (dsub * 16 + l15) * 68 + nt * 16 + quad * 4;
        f32x4 v4 = *(const f32x4*)p + yt[nt][dsub];
#pragma unroll
        for (int r = 0; r < 4; r++)
          pbuf[(nt * 16 + quad * 4 + r) * 72 + dsub * 16 + l15] = f2bf(v4[r]);
      }
  }
  __syncthreads();

  // coalesced copy pbuf -> Yp[ih][b][j0+row][d]
  ushort_t* Ypb = Yp + ((size_t)(ih * 8 + b) * NTOK + j0) * DK;
#pragma unroll
  for (int kr = 0; kr < 2; kr++) {
    int s = tid + 256 * kr;
    int row = s >> 3, cc = (s & 7) * 8;
    *(uint4v*)(Ypb + (size_t)row * DK + cc) = *(const uint4v*)(pbuf + row * 72 + cc);
  }
}

// ---- k_out: y = Yp0 + Yp1 ; o = Wout @ y * gamma + x --------------------
__global__ __launch_bounds__(256) void k_out(const ushort_t* __restrict__ Yp,
                                             const ushort_t* __restrict__ Wout,
                                             const float* __restrict__ gammap,
                                             const float* __restrict__ x,
                                             float* __restrict__ outp) {
  const int id = blockIdx.x;                 // 512 blocks
  const int b = id & 7;
  const int n0 = (id >> 3) * 64;
  const int tid = threadIdx.x;
  const int lane = tid & 63, wv = tid >> 6;
  const int quad = lane >> 4, l15 = lane & 15;
  __shared__ __align__(16) ushort_t pbuf[64 * 72];

  const ushort_t* Y0 = Yp + ((size_t)b * NTOK + n0) * DK;
  const ushort_t* Y1 = Yp + ((size_t)(8 + b) * NTOK + n0) * DK;
#pragma unroll
  for (int kr = 0; kr < 2; kr++) {
    int s = tid + 256 * kr;
    int row = s >> 3, c8 = (s & 7) * 8;
    uint4v ua = *(const uint4v*)(Y0 + (size_t)row * DK + c8);
    uint4v ub = *(const uint4v*)(Y1 + (size_t)row * DK + c8);
    uint4v oc;
    unsigned* pa = (unsigned*)&ua;
    unsigned* pb = (unsigned*)&ub;
    unsigned* po = (unsigned*)&oc;
#pragma unroll
    for (int w = 0; w < 4; w++) {
      float lo = bf2f((ushort_t)(pa[w] & 0xffff)) + bf2f((ushort_t)(pb[w] & 0xffff));
      float hi = bf2f((ushort_t)(pa[w] >> 16)) + bf2f((ushort_t)(pb[w] >> 16));
      po[w] = bfpack(lo, hi);
    }
    *(uint4v*)(pbuf + row * 72 + c8) = oc;
  }
  __syncthreads();

  const f32x4 zero4 = {0.f, 0.f, 0.f, 0.f};
  bf16x8 yb0[4], yb1[4];
#pragma unroll
  for (int nt = 0; nt < 4; nt++) {
    yb0[nt] = lds_frag(pbuf + (nt * 16 + l15) * 72 + quad * 8);
    yb1[nt] = lds_frag(pbuf + (nt * 16 + l15) * 72 + 32 + quad * 8);
  }
  f32x4 oacc[4][4];
#pragma unroll
  for (int m = 0; m < 4; m++)
#pragma unroll
    for (int nt = 0; nt < 4; nt++) oacc[m][nt] = zero4;
#pragma unroll
  for (int m = 0; m < 4; m++) {
    int c = (wv * 4 + m) * 16 + l15;
    bf16x8 aw0 = __builtin_bit_cast(bf16x8, *(const uint4v*)(Wout + c * DK + quad * 8));
    bf16x8 aw1 = __builtin_bit_cast(bf16x8, *(const uint4v*)(Wout + c * DK + 32 + quad * 8));
#pragma unroll
    for (int nt = 0; nt < 4; nt++) {
      oacc[m][nt] = __builtin_amdgcn_mfma_f32_16x16x32_bf16(aw0, yb0[nt], oacc[m][nt], 0, 0, 0);
      oacc[m][nt] = __builtin_amdgcn_mfma_f32_16x16x32_bf16(aw1, yb1[nt], oacc[m][nt], 0, 0, 0);
    }
  }
  float g = gammap[0];
  const float* xb = x + (size_t)b * DMODEL * NTOK;
  float* ob = outp + (size_t)b * DMODEL * NTOK;
#pragma unroll
  for (int m = 0; m < 4; m++) {
    int cbase = (wv * 4 + m) * 16 + quad * 4;
#pragma unroll
    for (int nt = 0; nt < 4; nt++) {
      int n = n0 + nt * 16 + l15;
#pragma unroll
      for (int r = 0; r < 4; r++) {
        size_t idx = (size_t)(cbase + r) * NTOK + n;
        ob[idx] = oacc[m][nt][r] * g + xb[idx];
      }
    }
  }
}

extern "C" void kernel_launch(void* const* d_in, const int* in_sizes, int n_in,
                              void* d_out, int out_size, void* d_ws, size_t ws_size,
                              hipStream_t stream) {
  const float* v = (const float*)d_in[0];
  const float* Wqkv = (const float*)d_in[1];
  const float* Wout = (const float*)d_in[2];
  const float* gamma = (const float*)d_in[3];
  float* outp = (float*)d_out;

  ushort_t* QT = (ushort_t*)d_ws;                      // 8*4096*64 bf16
  ushort_t* KT = QT + (size_t)BS * NTOK * DK;
  ushort_t* Vf = KT + (size_t)BS * NTOK * DK;          // fragment-order V
  ushort_t* Wb = Vf + (size_t)BS * DK * NTOK;          // 192*256
  ushort_t* Woutb = Wb + 3 * DK * DMODEL;              // 256*64
  float* Rr = (float*)(Woutb + DMODEL * DK);           // 8*4096 f32
  ushort_t* Yp = (ushort_t*)(Rr + (size_t)BS * NTOK);  // 2*8*4096*64 bf16

  k_convert<<<dim3(256), 256, 0, stream>>>(Wqkv, Wout, Wb, Woutb);
  k_qkv<<<dim3(64, BS), 256, 0, stream>>>(v, Wb, QT, KT, Vf);
  k_rsum<<<dim3(512), 512, 0, stream>>>(QT, KT, Rr);
  k_pv<<<dim3(1024), 256, 0, stream>>>(QT, KT, Vf, Rr, Yp);
  k_out<<<dim3(512), 256, 0, stream>>>(Yp, Woutb, gamma, v, outp);
}

// Round 11
// 185.303 us; speedup vs baseline: 1.2096x; 1.0848x over previous
//
#include <hip/hip_runtime.h>

typedef unsigned short ushort_t;
typedef __bf16 bf16x8 __attribute__((ext_vector_type(8)));
typedef short short4v __attribute__((ext_vector_type(4)));
typedef float f32x4 __attribute__((ext_vector_type(4)));
typedef unsigned int uint4v __attribute__((ext_vector_type(4)));
typedef unsigned int uint2v __attribute__((ext_vector_type(2)));

#define NTOK 4096
#define DMODEL 256
#define DK 64
#define BS 8
#define LN2INV 1.44269504088896f

__device__ __forceinline__ ushort_t f2bf(float f) {
  unsigned u = __builtin_bit_cast(unsigned, f);
  u += 0x7fffu + ((u >> 16) & 1u);
  return (ushort_t)(u >> 16);
}
__device__ __forceinline__ float bf2f(ushort_t s) {
  return __builtin_bit_cast(float, ((unsigned)s) << 16);
}
__device__ __forceinline__ bf16x8 lds_frag(const ushort_t* p) {
  return __builtin_bit_cast(bf16x8, *(const uint4v*)p);
}
__device__ __forceinline__ bf16x8 ldg8(const ushort_t* p) {
  return __builtin_bit_cast(bf16x8, *(const uint4v*)p);
}
__device__ __forceinline__ short4v lo8(uint4v v) {
  uint2v t; t.x = v.x; t.y = v.y;
  return __builtin_bit_cast(short4v, t);
}
__device__ __forceinline__ short4v hi8(uint4v v) {
  uint2v t; t.x = v.z; t.y = v.w;
  return __builtin_bit_cast(short4v, t);
}
__device__ __forceinline__ float fexp2(float x) {
#if __has_builtin(__builtin_amdgcn_exp2f)
  return __builtin_amdgcn_exp2f(x);
#else
  return exp2f(x);
#endif
}
// pack hi16(x) | hi16(y)<<16 in one v_perm (bf16 truncation)
__device__ __forceinline__ unsigned bfpack(float x, float y) {
  return __builtin_amdgcn_perm(__builtin_bit_cast(unsigned, y),
                               __builtin_bit_cast(unsigned, x), 0x07060302u);
}
// K=16 bf16 MFMA: A[m=lane&15][k=quad*4+j], B[k=quad*4+j][n=lane&15], C: n=lane&15, m=quad*4+reg
__device__ __forceinline__ f32x4 mfma16(short4v a, short4v b, f32x4 c) {
#if defined(__HIP_DEVICE_COMPILE__)
#if __has_builtin(__builtin_amdgcn_mfma_f32_16x16x16bf16_1k)
  return __builtin_amdgcn_mfma_f32_16x16x16bf16_1k(a, b, c, 0, 0, 0);
#else
  typedef __bf16 bf16x4 __attribute__((ext_vector_type(4)));
  return __builtin_amdgcn_mfma_f32_16x16x16_bf16(__builtin_bit_cast(bf16x4, a),
                                                 __builtin_bit_cast(bf16x4, b), c, 0, 0, 0);
#endif
#else
  (void)a; (void)b;
  return c;  // host pass: never executed
#endif
}

// async global->LDS DMA, 16B per lane; dest = (uniform base) + lane*16
typedef __attribute__((address_space(3))) unsigned int lds_u32;
typedef const __attribute__((address_space(1))) unsigned int glob_u32;
__device__ __forceinline__ void gll16(const void* g, void* l) {
#if defined(__HIP_DEVICE_COMPILE__)
  __builtin_amdgcn_global_load_lds((glob_u32*)g, (lds_u32*)l, 16, 0, 0);
#else
  (void)g; (void)l;
#endif
}

// ----- k_convert: W fp32 -> bf16; Q rows pre-scaled by 1/ln2 (exp2 trick) --
__global__ __launch_bounds__(256) void k_convert(const float* __restrict__ Wqkv,
                                                 const float* __restrict__ Wout,
                                                 ushort_t* __restrict__ Wb,
                                                 ushort_t* __restrict__ Woutb) {
  int i = blockIdx.x * 256 + threadIdx.x;  // 256 blocks: 65536 total
  if (i < 3 * DK * DMODEL) {
    float w = Wqkv[i];
    if (i < DK * DMODEL) w *= LN2INV;  // Q rows
    Wb[i] = f2bf(w);
  } else {
    int j = i - 3 * DK * DMODEL;
    Woutb[j] = f2bf(Wout[j]);
  }
}

// ---------------- k1 v4: qkv = Wqkv @ x ; fused transpose + coalesced out --
__global__ __launch_bounds__(256) void k_qkv(const float* __restrict__ x,
                                             const ushort_t* __restrict__ W,
                                             ushort_t* __restrict__ QT,
                                             ushort_t* __restrict__ KT,
                                             ushort_t* __restrict__ Vf) {
  const int b = blockIdx.y;
  const int n0 = blockIdx.x * 64;
  const int tid = threadIdx.x;
  const int lane = tid & 63, wv = tid >> 6;
  const int quad = lane >> 4, l15 = lane & 15;
  __shared__ __align__(16) ushort_t lx[64 * 264];
  __shared__ __align__(16) ushort_t t[64 * 72];

  const float* xb = x + (size_t)b * DMODEL * NTOK;

  // ---- transpose prologue: 4 chunks of 64 c ----
#pragma unroll 1
  for (int cc = 0; cc < 4; cc++) {
    const int c0chunk = cc * 64;
#pragma unroll
    for (int kr = 0; kr < 2; kr++) {
      int s = tid + 256 * kr;
      int c = s >> 3, ns = (s & 7) * 8;
      const float* src = xb + (size_t)(c0chunk + c) * NTOK + n0 + ns;
      f32x4 a = *(const f32x4*)src;
      f32x4 bq = *(const f32x4*)(src + 4);
      uint4v o;
      o.x = (unsigned)f2bf(a[0]) | ((unsigned)f2bf(a[1]) << 16);
      o.y = (unsigned)f2bf(a[2]) | ((unsigned)f2bf(a[3]) << 16);
      o.z = (unsigned)f2bf(bq[0]) | ((unsigned)f2bf(bq[1]) << 16);
      o.w = (unsigned)f2bf(bq[2]) | ((unsigned)f2bf(bq[3]) << 16);
      *(uint4v*)(t + c * 72 + ns) = o;
    }
    __syncthreads();
#pragma unroll
    for (int kr = 0; kr < 2; kr++) {
      int s = tid + 256 * kr;
      int n = s >> 3, cs = (s & 7) * 8;
      unsigned e0 = t[(cs + 0) * 72 + n], e1 = t[(cs + 1) * 72 + n];
      unsigned e2 = t[(cs + 2) * 72 + n], e3 = t[(cs + 3) * 72 + n];
      unsigned e4 = t[(cs + 4) * 72 + n], e5 = t[(cs + 5) * 72 + n];
      unsigned e6 = t[(cs + 6) * 72 + n], e7 = t[(cs + 7) * 72 + n];
      uint4v o;
      o.x = e0 | (e1 << 16); o.y = e2 | (e3 << 16);
      o.z = e4 | (e5 << 16); o.w = e6 | (e7 << 16);
      *(uint4v*)(lx + n * 264 + c0chunk + cs) = o;
    }
    __syncthreads();
  }

  // ---- main loop: barrier-free ----
  f32x4 acc[3][4];
  const f32x4 zero4 = {0.f, 0.f, 0.f, 0.f};
#pragma unroll
  for (int i = 0; i < 3; i++)
#pragma unroll
    for (int j = 0; j < 4; j++) acc[i][j] = zero4;

#pragma unroll
  for (int c0 = 0; c0 < DMODEL; c0 += 32) {
    bf16x8 aw[3];
#pragma unroll
    for (int mt = 0; mt < 3; mt++)
      aw[mt] = ldg8(W + (wv * 48 + mt * 16 + l15) * DMODEL + c0 + quad * 8);
    bf16x8 bb[4];
#pragma unroll
    for (int nt = 0; nt < 4; nt++)
      bb[nt] = lds_frag(lx + (nt * 16 + l15) * 264 + c0 + quad * 8);
#pragma unroll
    for (int mt = 0; mt < 3; mt++)
#pragma unroll
      for (int nt = 0; nt < 4; nt++)
        acc[mt][nt] = __builtin_amdgcn_mfma_f32_16x16x32_bf16(aw[mt], bb[nt], acc[mt][nt], 0, 0, 0);
  }

  // ---- epilogue: stage in LDS (overlay lx), then coalesced stores ----
  __syncthreads();  // all waves done reading lx
  ushort_t* qk_t = lx;            // 128 rows x 68 shorts (Q rows 0-63, K rows 64-127)
  ushort_t* v_t = lx + 128 * 68;  // 4096 shorts: the block's contiguous Vf tile
#pragma unroll
  for (int mt = 0; mt < 3; mt++) {
    int o = wv * 48 + mt * 16 + quad * 4;
#pragma unroll
    for (int nt = 0; nt < 4; nt++) {
      int nl = nt * 16 + l15;
      f32x4 v4 = acc[mt][nt];
      if (o < 128) {
        uint2v ww;
        ww.x = (unsigned)f2bf(v4[0]) | ((unsigned)f2bf(v4[1]) << 16);
        ww.y = (unsigned)f2bf(v4[2]) | ((unsigned)f2bf(v4[3]) << 16);
        int row = (o < 64) ? nl : 64 + nl;
        *(uint2v*)(qk_t + row * 68 + (o & 63)) = ww;
      } else {
        int dbase = o - 128;
        int idx = (nt * 2 + (dbase >> 5)) * 512 + ((l15 >> 2) << 7) +
                  ((dbase & 15) << 3) + (((dbase >> 4) & 1) << 2) + (l15 & 3);
#pragma unroll
        for (int r = 0; r < 4; r++) v_t[idx + (r << 3)] = f2bf(v4[r]);
      }
    }
  }
  __syncthreads();
  {
    ushort_t* QTb = QT + ((size_t)b * NTOK + n0) * DK;
    ushort_t* KTb = KT + ((size_t)b * NTOK + n0) * DK;
#pragma unroll
    for (int k = 0; k < 4; k++) {
      int s = tid + 256 * k;
      int row = s >> 3, seg = (s & 7) * 8;
      uint4v val = *(const uint4v*)(qk_t + row * 68 + seg);
      ushort_t* dst = (row < 64) ? (QTb + (size_t)row * DK + seg)
                                 : (KTb + (size_t)(row - 64) * DK + seg);
      *(uint4v*)dst = val;
    }
    ushort_t* Vtile = Vf + ((size_t)b * 64 + (n0 >> 6)) * 4096;
    *(uint4v*)(Vtile + tid * 8) = *(const uint4v*)(v_t + tid * 8);
    *(uint4v*)(Vtile + 2048 + tid * 8) = *(const uint4v*)(v_t + 2048 + tid * 8);
  }
}

// ---- k_rsum v6: full-j blocks, merge + -log2 fused ------------------------
__global__ __launch_bounds__(512, 4) void k_rsum(const ushort_t* __restrict__ QT,
                                                 const ushort_t* __restrict__ KT,
                                                 float* __restrict__ Rr) {
  const int id = blockIdx.x;                 // 512 blocks
  const int b = id & 7;                      // XCD affinity
  const int i0 = (id >> 3) * 64;
  const int tid = threadIdx.x;
  const int lane = tid & 63, wv = tid >> 6;  // wv in [0,8)
  const int quad = lane >> 4, l15 = lane & 15;
  __shared__ __align__(16) float partial[8 * 64];
  const ushort_t* QTb = QT + ((size_t)b * NTOK + i0) * DK;
  const ushort_t* KTb = KT + ((size_t)b * NTOK + wv * 512) * DK;

  // Q fragments for all 64 i's (one-time, coalesced)
  bf16x8 aq0[4], aq1[4];
#pragma unroll
  for (int isub = 0; isub < 4; isub++) {
    const ushort_t* qp = QTb + (size_t)(isub * 16 + l15) * DK + quad * 8;
    aq0[isub] = ldg8(qp);
    aq1[isub] = ldg8(qp + 32);
  }

  f32x4 racc[4];
  const f32x4 zero4 = {0.f, 0.f, 0.f, 0.f};
#pragma unroll
  for (int isub = 0; isub < 4; isub++) racc[isub] = zero4;

#pragma unroll 1
  for (int ph = 0; ph < 8; ph++) {
    const ushort_t* kb_base = KTb + (size_t)ph * 64 * DK;
    bf16x8 kb0[4], kb1[4];
#pragma unroll
    for (int nt = 0; nt < 4; nt++) {
      const ushort_t* kp = kb_base + (size_t)(nt * 16 + l15) * DK + quad * 8;
      kb0[nt] = ldg8(kp);
      kb1[nt] = ldg8(kp + 32);
    }
#pragma unroll
    for (int isub = 0; isub < 4; isub++)
#pragma unroll
      for (int nt = 0; nt < 4; nt++) {
        f32x4 s4 = __builtin_amdgcn_mfma_f32_16x16x32_bf16(aq0[isub], kb0[nt], zero4, 0, 0, 0);
        s4 = __builtin_amdgcn_mfma_f32_16x16x32_bf16(aq1[isub], kb1[nt], s4, 0, 0, 0);
        racc[isub][0] += fexp2(s4[0]);
        racc[isub][1] += fexp2(s4[1]);
        racc[isub][2] += fexp2(s4[2]);
        racc[isub][3] += fexp2(s4[3]);
      }
  }

  // reduce over the 16 j-lanes (l15); quad bits untouched by masks 1,2,4,8
#pragma unroll
  for (int isub = 0; isub < 4; isub++)
#pragma unroll
    for (int r = 0; r < 4; r++) {
      float v = racc[isub][r];
      v += __shfl_xor(v, 1);
      v += __shfl_xor(v, 2);
      v += __shfl_xor(v, 4);
      v += __shfl_xor(v, 8);
      racc[isub][r] = v;
    }
  if (l15 == 0) {
#pragma unroll
    for (int isub = 0; isub < 4; isub++)
      *(f32x4*)(partial + wv * 64 + isub * 16 + quad * 4) = racc[isub];
  }
  __syncthreads();
  if (tid < 64) {
    float s = 0.f;
#pragma unroll
    for (int w = 0; w < 8; w++) s += partial[w * 64 + tid];
    Rr[(size_t)b * NTOK + i0 + tid] = -__log2f(s);
  }
}

// ---- k_pv v10: v7 main loop (verbatim, per-wave) + fused output projection.
// 512 blocks x 512 threads (8 waves): waves 0-3 = old ih=0 block, waves 4-7 =
// old ih=1 block (ih = wv>>2, wq = wv&3). After the 8-wave yt reduction
// (two parallel 4-wave chains -> rbufA/rbufB, combined into pbuf), the k_out
// projection o = Wout @ y * gamma + x runs in-place: Yp buffer and the
// entire k_out kernel are eliminated.
__global__ __launch_bounds__(512, 4) void k_pv(const ushort_t* __restrict__ QT,
                                               const ushort_t* __restrict__ KT,
                                               const ushort_t* __restrict__ Vf,
                                               const float* __restrict__ Rr,
                                               const ushort_t* __restrict__ Wout,
                                               const float* __restrict__ gammap,
                                               const float* __restrict__ x,
                                               float* __restrict__ outp) {
  const int id = blockIdx.x;                 // 512 blocks
  const int b = id & 7;                      // XCD affinity
  const int j0 = (id >> 3) * 64;
  const int tid = threadIdx.x;
  const int lane = tid & 63, wv = tid >> 6;  // 8 waves
  const int quad = lane >> 4, l15 = lane & 15;
  const int ih = wv >> 2, wq = wv & 3;

  __shared__ __align__(16) ushort_t pool[24576];   // 49152 B
  float* lrtab = (float*)pool;                     // [0,16384): 4096 f32
  ushort_t* wbuf = pool + 8192 + wv * 2048;        // byte 16384 + wv*4096
  float* rbufA = (float*)pool;                     // epilogue: bytes [0,17408)
  float* rbufB = (float*)(pool + 8704);            // bytes [17408,34816)
  ushort_t* pbuf = pool + 17408;                   // bytes [34816,44032)

  const ushort_t* KTb = KT + ((size_t)b * NTOK + j0) * DK;
  const ushort_t* QTb = QT + ((size_t)b * NTOK + ih * 2048) * DK;
  const ushort_t* Vfb = Vf + ((size_t)b * 64 + ih * 32) * 4096;  // 8KB tiles
  const float* Rrb = Rr + (size_t)b * NTOK;

  const int qrow = (wq * 16 + l15) * DK + quad * 8;
  const int vfo = wq * 1024 + lane * 8;

  // issue it0 DMA first (overlaps lr-table staging + K loads)
  gll16(QTb + qrow,       wbuf);
  gll16(QTb + qrow + 32,  wbuf + 512);
  gll16(Vfb + vfo,        wbuf + 1024);
  gll16(Vfb + vfo + 512,  wbuf + 1536);

  // lr table: 4096 f32 (both halves), cooperative coalesced (512 thr x 8)
  {
    f32x4 r0 = *(const f32x4*)(Rrb + tid * 8);
    f32x4 r1 = *(const f32x4*)(Rrb + tid * 8 + 4);
    *(f32x4*)(lrtab + tid * 8) = r0;
    *(f32x4*)(lrtab + tid * 8 + 4) = r1;
  }

  // resident K tile, one-time direct-global per wave
  bf16x8 kb0[4], kb1[4];
#pragma unroll
  for (int nt = 0; nt < 4; nt++) {
    const ushort_t* kp = KTb + (size_t)(nt * 16 + l15) * DK + quad * 8;
    kb0[nt] = ldg8(kp);
    kb1[nt] = ldg8(kp + 32);
  }

  __syncthreads();  // lrtab visible; drains vmcnt -> buf0 complete

  f32x4 yt[4][4];
  const f32x4 zero4 = {0.f, 0.f, 0.f, 0.f};
#pragma unroll
  for (int i = 0; i < 4; i++)
#pragma unroll
    for (int j = 0; j < 4; j++) yt[i][j] = zero4;

#pragma unroll 1
  for (int it = 0; it < 32; it++) {
    const int cb = it & 1, nb = cb ^ 1;
    const int tpre = (it + 1 < 32) ? it + 1 : 31;  // always issue (keeps vmcnt math)
    {
      const ushort_t* qp = QTb + (size_t)tpre * 64 * DK + qrow;
      const ushort_t* vp = Vfb + (size_t)tpre * 4096 + vfo;
      ushort_t* nbuf = wbuf + nb * 2048;
      gll16(qp,       nbuf);
      gll16(qp + 32,  nbuf + 512);
      gll16(vp,       nbuf + 1024);
      gll16(vp + 512, nbuf + 1536);
    }
    asm volatile("s_waitcnt vmcnt(4)" ::: "memory");  // prev it's DMA done
    __builtin_amdgcn_sched_barrier(0);
    const ushort_t* cbuf = wbuf + cb * 2048;
    bf16x8 a0 = lds_frag(cbuf + lane * 8);
    bf16x8 a1 = lds_frag(cbuf + 512 + lane * 8);
    uint4v vv0 = *(const uint4v*)(cbuf + 1024 + lane * 8);
    uint4v vv1 = *(const uint4v*)(cbuf + 1536 + lane * 8);
    f32x4 lrv = *(const f32x4*)(lrtab + ih * 2048 + it * 64 + wq * 16 + quad * 4);
    short4v vf0 = lo8(vv0), vf1 = hi8(vv0), vf2 = lo8(vv1), vf3 = hi8(vv1);
#pragma unroll
    for (int nt = 0; nt < 4; nt++) {
      f32x4 s4 = __builtin_amdgcn_mfma_f32_16x16x32_bf16(a0, kb0[nt], lrv, 0, 0, 0);
      s4 = __builtin_amdgcn_mfma_f32_16x16x32_bf16(a1, kb1[nt], s4, 0, 0, 0);
      uint2v wp;
      wp.x = bfpack(fexp2(s4[0]), fexp2(s4[1]));
      wp.y = bfpack(fexp2(s4[2]), fexp2(s4[3]));
      short4v wf = __builtin_bit_cast(short4v, wp);
      yt[nt][0] = mfma16(wf, vf0, yt[nt][0]);
      yt[nt][1] = mfma16(wf, vf1, yt[nt][1]);
      yt[nt][2] = mfma16(wf, vf2, yt[nt][2]);
      yt[nt][3] = mfma16(wf, vf3, yt[nt][3]);
    }
  }

  asm volatile("s_waitcnt vmcnt(0)" ::: "memory");  // drain dummy prefetch
  __syncthreads();  // all waves out of dbuf/lrtab region before overlay

  // two parallel 4-wave reduction chains: group ih=0 -> rbufA, ih=1 -> rbufB
  float* rb = (ih == 0) ? rbufA : rbufB;
  if (wq == 0) {
#pragma unroll
    for (int nt = 0; nt < 4; nt++)
#pragma unroll
      for (int dsub = 0; dsub < 4; dsub++)
        *(f32x4*)(rb + (dsub * 16 + l15) * 68 + nt * 16 + quad * 4) = yt[nt][dsub];
  }
  __syncthreads();
  if (wq == 1) {
#pragma unroll
    for (int nt = 0; nt < 4; nt++)
#pragma unroll
      for (int dsub = 0; dsub < 4; dsub++) {
        float* p = rb + (dsub * 16 + l15) * 68 + nt * 16 + quad * 4;
        *(f32x4*)p = *(const f32x4*)p + yt[nt][dsub];
      }
  }
  __syncthreads();
  if (wq == 2) {
#pragma unroll
    for (int nt = 0; nt < 4; nt++)
#pragma unroll
      for (int dsub = 0; dsub < 4; dsub++) {
        float* p = rb + (dsub * 16 + l15) * 68 + nt * 16 + quad * 4;
        *(f32x4*)p = *(const f32x4*)p + yt[nt][dsub];
      }
  }
  __syncthreads();
  if (wq == 3) {
#pragma unroll
    for (int nt = 0; nt < 4; nt++)
#pragma unroll
      for (int dsub = 0; dsub < 4; dsub++) {
        float* p = rb + (dsub * 16 + l15) * 68 + nt * 16 + quad * 4;
        *(f32x4*)p = *(const f32x4*)p + yt[nt][dsub];
      }
  }
  __syncthreads();
  // combine A+B -> bf16 pbuf[j][d]; wave wv covers nt = wv&3, dsub pair wv>>2
  {
    const int nt = wv & 3;
#pragma unroll
    for (int k = 0; k < 2; k++) {
      const int dsub = (wv >> 2) * 2 + k;
      const float* pA = rbufA + (dsub * 16 + l15) * 68 + nt * 16 + quad * 4;
      const float* pB = rbufB + (dsub * 16 + l15) * 68 + nt * 16 + quad * 4;
      f32x4 v4 = *(const f32x4*)pA + *(const f32x4*)pB;
#pragma unroll
      for (int r = 0; r < 4; r++)
        pbuf[(nt * 16 + quad * 4 + r) * 72 + dsub * 16 + l15] = f2bf(v4[r]);
    }
  }
  __syncthreads();

  // ---- fused projection: o = Wout @ y * gamma + x (k_out body, m-width 2) --
  bf16x8 yb0[4], yb1[4];
#pragma unroll
  for (int nt = 0; nt < 4; nt++) {
    yb0[nt] = lds_frag(pbuf + (nt * 16 + l15) * 72 + quad * 8);
    yb1[nt] = lds_frag(pbuf + (nt * 16 + l15) * 72 + 32 + quad * 8);
  }
  f32x4 oacc[2][4];
#pragma unroll
  for (int m = 0; m < 2; m++)
#pragma unroll
    for (int nt = 0; nt < 4; nt++) oacc[m][nt] = zero4;
#pragma unroll
  for (int m = 0; m < 2; m++) {
    int c = (wv * 2 + m) * 16 + l15;
    bf16x8 aw0 = __builtin_bit_cast(bf16x8, *(const uint4v*)(Wout + c * DK + quad * 8));
    bf16x8 aw1 = __builtin_bit_cast(bf16x8, *(const uint4v*)(Wout + c * DK + 32 + quad * 8));
#pragma unroll
    for (int nt = 0; nt < 4; nt++) {
      oacc[m][nt] = __builtin_amdgcn_mfma_f32_16x16x32_bf16(aw0, yb0[nt], oacc[m][nt], 0, 0, 0);
      oacc[m][nt] = __builtin_amdgcn_mfma_f32_16x16x32_bf16(aw1, yb1[nt], oacc[m][nt], 0, 0, 0);
    }
  }
  float g = gammap[0];
  const float* xb = x + (size_t)b * DMODEL * NTOK;
  float* ob = outp + (size_t)b * DMODEL * NTOK;
#pragma unroll
  for (int m = 0; m < 2; m++) {
    int cbase = (wv * 2 + m) * 16 + quad * 4;
#pragma unroll
    for (int nt = 0; nt < 4; nt++) {
      int n = j0 + nt * 16 + l15;
#pragma unroll
      for (int r = 0; r < 4; r++) {
        size_t idx = (size_t)(cbase + r) * NTOK + n;
        ob[idx] = oacc[m][nt][r] * g + xb[idx];
      }
    }
  }
}

extern "C" void kernel_launch(void* const* d_in, const int* in_sizes, int n_in,
                              void* d_out, int out_size, void* d_ws, size_t ws_size,
                              hipStream_t stream) {
  const float* v = (const float*)d_in[0];
  const float* Wqkv = (const float*)d_in[1];
  const float* Wout = (const float*)d_in[2];
  const float* gamma = (const float*)d_in[3];
  float* outp = (float*)d_out;

  ushort_t* QT = (ushort_t*)d_ws;                      // 8*4096*64 bf16
  ushort_t* KT = QT + (size_t)BS * NTOK * DK;
  ushort_t* Vf = KT + (size_t)BS * NTOK * DK;          // fragment-order V
  ushort_t* Wb = Vf + (size_t)BS * DK * NTOK;          // 192*256
  ushort_t* Woutb = Wb + 3 * DK * DMODEL;              // 256*64
  float* Rr = (float*)(Woutb + DMODEL * DK);           // 8*4096 f32

  k_convert<<<dim3(256), 256, 0, stream>>>(Wqkv, Wout, Wb, Woutb);
  k_qkv<<<dim3(64, BS), 256, 0, stream>>>(v, Wb, QT, KT, Vf);
  k_rsum<<<dim3(512), 512, 0, stream>>>(QT, KT, Rr);
  k_pv<<<dim3(512), 512, 0, stream>>>(QT, KT, Vf, Rr, Woutb, gamma, v, outp);
}